// Round 10
// baseline (523.847 us; speedup 1.0000x reference)
//
#include <hip/hip_runtime.h>

typedef unsigned int u32;
typedef unsigned char u8;

#define M_DIM 8192   // B*S = 4*2048
#define K_DIM 4096   // I
#define N_DIM 4096   // O
#define GROUPS 64    // I / GROUP_SIZE

typedef int intx4 __attribute__((ext_vector_type(4)));

__device__ __forceinline__ void gload_lds16(const void* g, void* l) {
  __builtin_amdgcn_global_load_lds(
      (const __attribute__((address_space(1))) void*)g,
      (__attribute__((address_space(3))) void*)l, 16, 0, 0);
}

__device__ __forceinline__ u32 pack4(const float* v, float inv) {
  u32 r = 0;
#pragma unroll
  for (int i = 0; i < 4; ++i) {
    int q = (int)__builtin_rintf(v[i] * inv);
    q = q > 127 ? 127 : (q < -127 ? -127 : q);
    r |= ((u32)(u8)(char)q) << (8 * i);
  }
  return r;
}

// ---- fused prep (unchanged, verified) ----
__global__ __launch_bounds__(256) void prep_all(
    const float* __restrict__ x, const float* __restrict__ cs,
    const u32* __restrict__ qw, const int* __restrict__ perm,
    const float* __restrict__ scales, const float* __restrict__ zeros,
    u8* __restrict__ xq, u8* __restrict__ wq,
    float* __restrict__ sx, float* __restrict__ sw) {
  __shared__ float rowbuf[K_DIM];   // 16 KB (W path only)
  __shared__ float red[4];
  const int t = threadIdx.x;
  if (blockIdx.x < N_DIM) {
    const int base = t * 16;
    const int o = blockIdx.x;
    const u32* qrow = qw + (size_t)o * (K_DIM / 8);
    const float s = scales[o * GROUPS + (t >> 2)];
    const float z = zeros[o * GROUPS + (t >> 2)];
    uint2 w = *(const uint2*)(qrow + 2 * t);   // elements [16t, 16t+16)
    int4 p0 = *(const int4*)(perm + base + 0);
    int4 p1 = *(const int4*)(perm + base + 4);
    int4 p2 = *(const int4*)(perm + base + 8);
    int4 p3 = *(const int4*)(perm + base + 12);
    float v[16];
    float amax = 0.f;
#pragma unroll
    for (int n = 0; n < 8; ++n) {
      v[n]     = (float)((w.x >> (4 * n)) & 15u) * s + z;
      v[8 + n] = (float)((w.y >> (4 * n)) & 15u) * s + z;
      amax = fmaxf(amax, fmaxf(fabsf(v[n]), fabsf(v[8 + n])));
    }
    rowbuf[p0.x] = v[0];  rowbuf[p0.y] = v[1];
    rowbuf[p0.z] = v[2];  rowbuf[p0.w] = v[3];
    rowbuf[p1.x] = v[4];  rowbuf[p1.y] = v[5];
    rowbuf[p1.z] = v[6];  rowbuf[p1.w] = v[7];
    rowbuf[p2.x] = v[8];  rowbuf[p2.y] = v[9];
    rowbuf[p2.z] = v[10]; rowbuf[p2.w] = v[11];
    rowbuf[p3.x] = v[12]; rowbuf[p3.y] = v[13];
    rowbuf[p3.z] = v[14]; rowbuf[p3.w] = v[15];
#pragma unroll
    for (int off = 32; off; off >>= 1)
      amax = fmaxf(amax, __shfl_xor(amax, off, 64));
    if ((t & 63) == 0) red[t >> 6] = amax;
    __syncthreads();
    amax = fmaxf(fmaxf(red[0], red[1]), fmaxf(red[2], red[3]));
    amax = fmaxf(amax, 1e-20f);
    const float inv = 127.0f / amax;
    uint4 p;
    p.x = pack4(rowbuf + base + 0, inv);
    p.y = pack4(rowbuf + base + 4, inv);
    p.z = pack4(rowbuf + base + 8, inv);
    p.w = pack4(rowbuf + base + 12, inv);
    *(uint4*)(wq + (size_t)o * K_DIM + base) = p;
    if (t == 0) sw[o] = amax * (1.0f / 127.0f);
  } else {
    const int wave = t >> 6, lane = t & 63;
    const size_t m = (size_t)(blockIdx.x - N_DIM) * 4 + wave;
    const float* xr = x + m * K_DIM;
    float v[64];
    float amax = 0.f;
#pragma unroll
    for (int j = 0; j < 4; ++j) {
      const int col = j * 1024 + lane * 16;
#pragma unroll
      for (int u = 0; u < 4; ++u) {
        float4 xv = *(const float4*)(xr + col + u * 4);
        float4 cv = *(const float4*)(cs + col + u * 4);
        float* vp = v + j * 16 + u * 4;
        vp[0] = xv.x * cv.x;
        vp[1] = xv.y * cv.y;
        vp[2] = xv.z * cv.z;
        vp[3] = xv.w * cv.w;
        amax = fmaxf(amax, fmaxf(fmaxf(fabsf(vp[0]), fabsf(vp[1])),
                                 fmaxf(fabsf(vp[2]), fabsf(vp[3]))));
      }
    }
#pragma unroll
    for (int off = 32; off; off >>= 1)
      amax = fmaxf(amax, __shfl_xor(amax, off, 64));
    amax = fmaxf(amax, 1e-20f);
    const float inv = 127.0f / amax;
#pragma unroll
    for (int j = 0; j < 4; ++j) {
      uint4 p;
      p.x = pack4(v + j * 16 + 0, inv);
      p.y = pack4(v + j * 16 + 4, inv);
      p.z = pack4(v + j * 16 + 8, inv);
      p.w = pack4(v + j * 16 + 12, inv);
      *(uint4*)(xq + m * K_DIM + j * 1024 + lane * 16) = p;
    }
    if (lane == 0) sx[m] = amax * (1.0f / 127.0f);
  }
}

// ---- gemm: A DIRECT-TO-REGISTER, B LDS-staged. 256x128 tile, 4 waves ----
// Two-pipe accounting at 2 blocks/CU: MFMA 1306 cyc/tile, LDS-read
// 8 waves x 12 b128 x 12cyc = 1152 — CO-CRITICAL. Seven schedules pinned
// at 30-35% because rearranging reads can't fix parity demand. Fix:
// A-fragments bypass LDS (global->VGPR; pattern row*4096+q*16, panel
// L2/LLC-hot; traffic x2 accepted, ~13 TB/s vs 34.5 TB/s L2 ceiling).
// LDS reads drop 12 -> 4 per tile per wave (B only) => LDS pipe 384 cyc,
// MFMA sole critical pipe. A-regs: TWO NAMED sets (a0/a1, rule #20 — no
// runtime-indexed reg arrays), loaded one tile ahead; compiler auto-waits
// on the loads before MFMA use. vmcnt ledger (per wave, per tile: 2
// B-stage gload_lds + 8 A-loads = 10 issues): steady in-flight 20, one
// vmcnt(10)+barrier per tile certifies B(t+1)+A(t); drain peel 10/10/8/0.
// B path byte-identical to the verified r0/r9 zero-conflict scheme.
// setprio REMOVED (m190: hurts non-phase GEMM).
// __launch_bounds__(256,2) — never raise 2nd arg (r4 spill disaster).
#define BM 256
#define BN 128
#define BK 64
#define KTILES (K_DIM / BK)   // 64

__global__ __launch_bounds__(256, 2) void gemm_i8(
    const u8* __restrict__ A, const u8* __restrict__ B,
    const float* __restrict__ sx, const float* __restrict__ sw,
    const float* __restrict__ bias, float* __restrict__ out) {
  __shared__ __align__(16) u8 Bs[3][BN * BK];   // 3 x 8 KB (B only)
  const int tid = threadIdx.x;
  const int lane = tid & 63;
  const int wave = tid >> 6;           // 0..3
  const int wm = wave >> 1;            // 0..1 -> 128 M-rows each
  const int wn = wave & 1;             // 0..1 -> 64 N-cols each
  const int q = lane >> 4, lr = lane & 15;
  const int qs = q ^ ((lr >> 1) & 3);  // B frag read slot (verified)

  // XCD-aware bijective swizzle (1024 % 8 == 0)
  const int wg = blockIdx.x;
  const int swzwg = (wg & 7) * 128 + (wg >> 3);
  const int blockN = (swzwg & 31) * BN;   // 32 N-panels
  const int blockM = (swzwg >> 5) * BM;   // 32 M-panels

  const char* Bbase = (const char*)(B + (size_t)blockN * K_DIM);
  // A: per-wave direct-load base. Lane lane=q*16+lr supplies
  // A[row = wm*128 + mi*16 + lr][k = t*64 + q*16 .. +15]  (mi 0..7)
  const char* Aptr = (const char*)A +
      ((size_t)(blockM + wm * 128 + lr) * K_DIM + q * 16);

  // B staging: 512 chunks, 2/thread (verified swizzle: slot p of row r
  // holds global chunk p ^ ((r>>1)&3))
  const int c0 = tid, c1 = tid + 256;
  const int kcB0 = (c0 & 3) ^ ((c0 >> 3) & 3);
  const int kcB1 = (c1 & 3) ^ ((c1 >> 3) & 3);
  const size_t gOffB0 = (size_t)(c0 >> 2) * K_DIM + kcB0 * 16;
  const size_t gOffB1 = (size_t)(c1 >> 2) * K_DIM + kcB1 * 16;
  const int dOffB0 = c0 * 16, dOffB1 = c1 * 16;

  const int boff = (wn * 64 + lr) * 64 + qs * 16;    // + ni*1024

  intx4 acc[8][4];
#pragma unroll
  for (int i = 0; i < 8; ++i)
#pragma unroll
    for (int j = 0; j < 4; ++j) acc[i][j] = (intx4)0;

  intx4 a0[8], a1[8];   // named double-buffer, constant-indexed only

#define STAGE_B(T) do {                                          \
    const size_t koff_ = (size_t)(T) * BK;                       \
    u8* Bw_ = &Bs[(T) % 3][0];                                   \
    gload_lds16(Bbase + gOffB0 + koff_, Bw_ + dOffB0);           \
    gload_lds16(Bbase + gOffB1 + koff_, Bw_ + dOffB1);           \
  } while (0)

#define LOAD_A(T, AR) do {                                       \
    const char* ap_ = Aptr + (size_t)(T) * BK;                   \
    _Pragma("unroll")                                            \
    for (int mi = 0; mi < 8; ++mi)                               \
      AR[mi] = *(const intx4*)(ap_ + mi * (16 * K_DIM));         \
  } while (0)

#define TILE(T, AUSE, DOSTAGE, ALOADT, ALOAD) do {               \
    if (DOSTAGE) STAGE_B((T) + 2);                               \
    if (ALOADT) LOAD_A((T) + 1, ALOAD);                          \
    const u8* Bb_ = &Bs[(T) % 3][0];                             \
    intx4 bf[4];                                                 \
    _Pragma("unroll")                                            \
    for (int ni = 0; ni < 4; ++ni)                               \
      bf[ni] = *(const intx4*)(Bb_ + boff + ni * 1024);          \
    _Pragma("unroll")                                            \
    for (int mi = 0; mi < 8; ++mi)                               \
      _Pragma("unroll")                                          \
      for (int ni = 0; ni < 4; ++ni)                             \
        acc[mi][ni] = __builtin_amdgcn_mfma_i32_16x16x64_i8(     \
            AUSE[mi], bf[ni], acc[mi][ni], 0, 0, 0);             \
  } while (0)

#define VM10_BAR asm volatile("s_waitcnt vmcnt(10)\n\ts_barrier" ::: "memory")

  // prologue: B0,B1 staged; A0 loaded; full certify
  STAGE_B(0);
  STAGE_B(1);
  LOAD_A(0, a0);
  asm volatile("s_waitcnt vmcnt(0)\n\ts_barrier" ::: "memory");

  // main loop: tiles 0..59, x2 unrolled for named A-reg ping-pong
  for (int tt = 0; tt < KTILES - 4; tt += 2) {
    TILE(tt, a0, 1, 1, a1);
    VM10_BAR;
    TILE(tt + 1, a1, 1, 1, a0);
    VM10_BAR;
  }
  // peel tiles 60..63 with exact drain counts
  TILE(60, a0, 1, 1, a1);   // stages B62, loads A61
  VM10_BAR;
  TILE(61, a1, 1, 1, a0);   // stages B63, loads A62
  VM10_BAR;
  TILE(62, a0, 0, 1, a1);   // loads A63; in-flight <=18
  asm volatile("s_waitcnt vmcnt(8)\n\ts_barrier" ::: "memory");
  TILE(63, a1, 0, 0, a0);   // compiler waits A63 regs itself

#undef STAGE_B
#undef LOAD_A
#undef TILE
#undef VM10_BAR

  // epilogue (verified 16x16 C/D map): col slot = lane&15, row = quad*4+reg
#pragma unroll
  for (int ni = 0; ni < 4; ++ni) {
    const int col = blockN + wn * 64 + ni * 16 + lr;
    const float swv = sw[col];
    const float bv = bias[col];
#pragma unroll
    for (int mi = 0; mi < 8; ++mi) {
      const int row0 = blockM + wm * 128 + mi * 16 + q * 4;
#pragma unroll
      for (int r = 0; r < 4; ++r) {
        const float s = sx[row0 + r] * swv;
        out[(size_t)(row0 + r) * N_DIM + col] = (float)acc[mi][ni][r] * s + bv;
      }
    }
  }
}

extern "C" void kernel_launch(void* const* d_in, const int* in_sizes, int n_in,
                              void* d_out, int out_size, void* d_ws, size_t ws_size,
                              hipStream_t stream) {
  const float* x      = (const float*)d_in[0];
  const float* cs     = (const float*)d_in[1];
  const u32*   qw     = (const u32*)d_in[2];
  const int*   perm   = (const int*)d_in[3];
  const float* scales = (const float*)d_in[4];
  const float* zeros  = (const float*)d_in[5];
  const float* bias   = (const float*)d_in[6];
  float* out = (float*)d_out;

  u8* xq = (u8*)d_ws;                               // 32 MiB: M*K i8 (natural)
  u8* wq = xq + (size_t)M_DIM * K_DIM;              // 16 MiB: N*K i8 (perm-scattered)
  float* sx = (float*)(wq + (size_t)N_DIM * K_DIM); // 32 KiB
  float* sw = sx + M_DIM;                           // 16 KiB

  hipLaunchKernelGGL(prep_all, dim3(N_DIM + M_DIM / 4), dim3(256), 0, stream,
                     x, cs, qw, perm, scales, zeros, xq, wq, sx, sw);
  hipLaunchKernelGGL(gemm_i8, dim3((M_DIM / BM) * (N_DIM / BN)), dim3(256), 0,
                     stream, xq, wq, sx, sw, bias, out);
}

// Round 11
// 400.431 us; speedup vs baseline: 1.3082x; 1.3082x over previous
//
#include <hip/hip_runtime.h>

typedef unsigned int u32;
typedef unsigned char u8;

#define M_DIM 8192   // B*S = 4*2048
#define K_DIM 4096   // I
#define N_DIM 4096   // O
#define GROUPS 64    // I / GROUP_SIZE

typedef int intx4 __attribute__((ext_vector_type(4)));

__device__ __forceinline__ void gload_lds16(const void* g, void* l) {
  __builtin_amdgcn_global_load_lds(
      (const __attribute__((address_space(1))) void*)g,
      (__attribute__((address_space(3))) void*)l, 16, 0, 0);
}

__device__ __forceinline__ u32 pack4(const float* v, float inv) {
  u32 r = 0;
#pragma unroll
  for (int i = 0; i < 4; ++i) {
    int q = (int)__builtin_rintf(v[i] * inv);
    q = q > 127 ? 127 : (q < -127 ? -127 : q);
    r |= ((u32)(u8)(char)q) << (8 * i);
  }
  return r;
}

// ---- fused prep (unchanged, verified) ----
__global__ __launch_bounds__(256) void prep_all(
    const float* __restrict__ x, const float* __restrict__ cs,
    const u32* __restrict__ qw, const int* __restrict__ perm,
    const float* __restrict__ scales, const float* __restrict__ zeros,
    u8* __restrict__ xq, u8* __restrict__ wq,
    float* __restrict__ sx, float* __restrict__ sw) {
  __shared__ float rowbuf[K_DIM];   // 16 KB (W path only)
  __shared__ float red[4];
  const int t = threadIdx.x;
  if (blockIdx.x < N_DIM) {
    const int base = t * 16;
    const int o = blockIdx.x;
    const u32* qrow = qw + (size_t)o * (K_DIM / 8);
    const float s = scales[o * GROUPS + (t >> 2)];
    const float z = zeros[o * GROUPS + (t >> 2)];
    uint2 w = *(const uint2*)(qrow + 2 * t);   // elements [16t, 16t+16)
    int4 p0 = *(const int4*)(perm + base + 0);
    int4 p1 = *(const int4*)(perm + base + 4);
    int4 p2 = *(const int4*)(perm + base + 8);
    int4 p3 = *(const int4*)(perm + base + 12);
    float v[16];
    float amax = 0.f;
#pragma unroll
    for (int n = 0; n < 8; ++n) {
      v[n]     = (float)((w.x >> (4 * n)) & 15u) * s + z;
      v[8 + n] = (float)((w.y >> (4 * n)) & 15u) * s + z;
      amax = fmaxf(amax, fmaxf(fabsf(v[n]), fabsf(v[8 + n])));
    }
    rowbuf[p0.x] = v[0];  rowbuf[p0.y] = v[1];
    rowbuf[p0.z] = v[2];  rowbuf[p0.w] = v[3];
    rowbuf[p1.x] = v[4];  rowbuf[p1.y] = v[5];
    rowbuf[p1.z] = v[6];  rowbuf[p1.w] = v[7];
    rowbuf[p2.x] = v[8];  rowbuf[p2.y] = v[9];
    rowbuf[p2.z] = v[10]; rowbuf[p2.w] = v[11];
    rowbuf[p3.x] = v[12]; rowbuf[p3.y] = v[13];
    rowbuf[p3.z] = v[14]; rowbuf[p3.w] = v[15];
#pragma unroll
    for (int off = 32; off; off >>= 1)
      amax = fmaxf(amax, __shfl_xor(amax, off, 64));
    if ((t & 63) == 0) red[t >> 6] = amax;
    __syncthreads();
    amax = fmaxf(fmaxf(red[0], red[1]), fmaxf(red[2], red[3]));
    amax = fmaxf(amax, 1e-20f);
    const float inv = 127.0f / amax;
    uint4 p;
    p.x = pack4(rowbuf + base + 0, inv);
    p.y = pack4(rowbuf + base + 4, inv);
    p.z = pack4(rowbuf + base + 8, inv);
    p.w = pack4(rowbuf + base + 12, inv);
    *(uint4*)(wq + (size_t)o * K_DIM + base) = p;
    if (t == 0) sw[o] = amax * (1.0f / 127.0f);
  } else {
    const int wave = t >> 6, lane = t & 63;
    const size_t m = (size_t)(blockIdx.x - N_DIM) * 4 + wave;
    const float* xr = x + m * K_DIM;
    float v[64];
    float amax = 0.f;
#pragma unroll
    for (int j = 0; j < 4; ++j) {
      const int col = j * 1024 + lane * 16;
#pragma unroll
      for (int u = 0; u < 4; ++u) {
        float4 xv = *(const float4*)(xr + col + u * 4);
        float4 cv = *(const float4*)(cs + col + u * 4);
        float* vp = v + j * 16 + u * 4;
        vp[0] = xv.x * cv.x;
        vp[1] = xv.y * cv.y;
        vp[2] = xv.z * cv.z;
        vp[3] = xv.w * cv.w;
        amax = fmaxf(amax, fmaxf(fmaxf(fabsf(vp[0]), fabsf(vp[1])),
                                 fmaxf(fabsf(vp[2]), fabsf(vp[3]))));
      }
    }
#pragma unroll
    for (int off = 32; off; off >>= 1)
      amax = fmaxf(amax, __shfl_xor(amax, off, 64));
    amax = fmaxf(amax, 1e-20f);
    const float inv = 127.0f / amax;
#pragma unroll
    for (int j = 0; j < 4; ++j) {
      uint4 p;
      p.x = pack4(v + j * 16 + 0, inv);
      p.y = pack4(v + j * 16 + 4, inv);
      p.z = pack4(v + j * 16 + 8, inv);
      p.w = pack4(v + j * 16 + 12, inv);
      *(uint4*)(xq + m * K_DIM + j * 1024 + lane * 16) = p;
    }
    if (lane == 0) sx[m] = amax * (1.0f / 127.0f);
  }
}

// ---- gemm: FAT-WAVE x 3 BLOCKS/CU. 256x128 tile, 4 waves, dbuf 48 KB ----
// Campaign closure: A/B-direct fatal (r10: cache-hierarchy saturation);
// distance-2 null (r5==r8); phases/shape null. Real wins: fat-wave
// (12 reads : 32 MFMA, 6B/MFMA — r9 −18us) and multi-block TLP. r9's
// tri-buffer (72 KB) capped residency at 2 blocks/CU; distance is proven
// irrelevant, so: DOUBLE-buffer 48 KB -> 3 blocks/CU by LDS (VGPR 128
// admits 4). Third independent block absorbs the latency/sync slack
// (measured 3206 cyc/tile vs two-pipe floor ~1540).
// Schedule (r5's proven ledger): { stage(t+1 -> nxt); 12 ds_read; 32
// MFMA (setprio); vmcnt(0); s_barrier } — vmcnt(0) waits on loads that
// had the full MFMA window (~1300+ cyc) to land.
// LDS scheme: round-0 verified-zero-conflict. Chunk c (row r=c>>2, slot
// p=c&3) holds global chunk p ^ ((r>>1)&3); frag read slot
// qs = q ^ ((lr>>1)&3). __launch_bounds__(256,2) — never raise 2nd arg
// (r4: (512,4) forced 64-VGPR cap -> 13 GB scratch).
#define BM 256
#define BN 128
#define BK 64
#define KTILES (K_DIM / BK)   // 64

__global__ __launch_bounds__(256, 2) void gemm_i8(
    const u8* __restrict__ A, const u8* __restrict__ B,
    const float* __restrict__ sx, const float* __restrict__ sw,
    const float* __restrict__ bias, float* __restrict__ out) {
  __shared__ __align__(16) u8 As[2][BM * BK];   // 2 x 16 KB
  __shared__ __align__(16) u8 Bs[2][BN * BK];   // 2 x 8 KB
  const int tid = threadIdx.x;
  const int lane = tid & 63;
  const int wave = tid >> 6;           // 0..3
  const int wm = wave >> 1;            // 0..1 -> 128 M-rows each
  const int wn = wave & 1;             // 0..1 -> 64 N-cols each
  const int q = lane >> 4, lr = lane & 15;
  const int qs = q ^ ((lr >> 1) & 3);  // verified conflict-free read slot

  // XCD-aware bijective swizzle (1024 % 8 == 0)
  const int wg = blockIdx.x;
  const int swzwg = (wg & 7) * 128 + (wg >> 3);
  const int blockN = (swzwg & 31) * BN;   // 32 N-panels
  const int blockM = (swzwg >> 5) * BM;   // 32 M-panels

  const char* Abase = (const char*)(A + (size_t)blockM * K_DIM);
  const char* Bbase = (const char*)(B + (size_t)blockN * K_DIM);

  // staging: A 1024 chunks (4/thread), B 512 chunks (2/thread)
  size_t gOffA[4]; int dOffA[4];
#pragma unroll
  for (int j = 0; j < 4; ++j) {
    const int c = tid + 256 * j;
    const int kc = (c & 3) ^ ((c >> 3) & 3);
    gOffA[j] = (size_t)(c >> 2) * K_DIM + kc * 16;
    dOffA[j] = c * 16;
  }
  size_t gOffB[2]; int dOffB[2];
#pragma unroll
  for (int j = 0; j < 2; ++j) {
    const int c = tid + 256 * j;
    const int kc = (c & 3) ^ ((c >> 3) & 3);
    gOffB[j] = (size_t)(c >> 2) * K_DIM + kc * 16;
    dOffB[j] = c * 16;
  }

  const int aoff = (wm * 128 + lr) * 64 + qs * 16;   // + mi*1024, mi 0..7
  const int boff = (wn * 64 + lr) * 64 + qs * 16;    // + ni*1024, ni 0..3

  intx4 acc[8][4];
#pragma unroll
  for (int i = 0; i < 8; ++i)
#pragma unroll
    for (int j = 0; j < 4; ++j) acc[i][j] = (intx4)0;

  auto stage = [&](int t, int b) {
    const size_t koff = (size_t)t * BK;
#pragma unroll
    for (int j = 0; j < 4; ++j)
      gload_lds16(Abase + gOffA[j] + koff, &As[b][dOffA[j]]);
#pragma unroll
    for (int j = 0; j < 2; ++j)
      gload_lds16(Bbase + gOffB[j] + koff, &Bs[b][dOffB[j]]);
  };

  // prologue
  stage(0, 0);
  asm volatile("s_waitcnt vmcnt(0)" ::: "memory");
  asm volatile("s_barrier" ::: "memory");

  for (int t = 0; t < KTILES; ++t) {
    const int cur = t & 1;
    if (t + 1 < KTILES) stage(t + 1, cur ^ 1);

    const u8* Ab = &As[cur][0];
    const u8* Bb = &Bs[cur][0];
    intx4 bf[4], af[8];
#pragma unroll
    for (int ni = 0; ni < 4; ++ni)
      bf[ni] = *(const intx4*)(Bb + boff + ni * 1024);
#pragma unroll
    for (int mi = 0; mi < 8; ++mi)
      af[mi] = *(const intx4*)(Ab + aoff + mi * 1024);

    __builtin_amdgcn_s_setprio(1);
#pragma unroll
    for (int mi = 0; mi < 8; ++mi)
#pragma unroll
      for (int ni = 0; ni < 4; ++ni)
        acc[mi][ni] = __builtin_amdgcn_mfma_i32_16x16x64_i8(
            af[mi], bf[ni], acc[mi][ni], 0, 0, 0);
    __builtin_amdgcn_s_setprio(0);

    if (t + 1 < KTILES) {
      asm volatile("s_waitcnt vmcnt(0)" ::: "memory");   // t+1 landed
      asm volatile("s_barrier" ::: "memory");            // cur fully read
    }
  }

  // epilogue (verified 16x16 C/D map): col slot = lane&15, row = quad*4+reg
#pragma unroll
  for (int ni = 0; ni < 4; ++ni) {
    const int col = blockN + wn * 64 + ni * 16 + lr;
    const float swv = sw[col];
    const float bv = bias[col];
#pragma unroll
    for (int mi = 0; mi < 8; ++mi) {
      const int row0 = blockM + wm * 128 + mi * 16 + q * 4;
#pragma unroll
      for (int r = 0; r < 4; ++r) {
        const float s = sx[row0 + r] * swv;
        out[(size_t)(row0 + r) * N_DIM + col] = (float)acc[mi][ni][r] * s + bv;
      }
    }
  }
}

extern "C" void kernel_launch(void* const* d_in, const int* in_sizes, int n_in,
                              void* d_out, int out_size, void* d_ws, size_t ws_size,
                              hipStream_t stream) {
  const float* x      = (const float*)d_in[0];
  const float* cs     = (const float*)d_in[1];
  const u32*   qw     = (const u32*)d_in[2];
  const int*   perm   = (const int*)d_in[3];
  const float* scales = (const float*)d_in[4];
  const float* zeros  = (const float*)d_in[5];
  const float* bias   = (const float*)d_in[6];
  float* out = (float*)d_out;

  u8* xq = (u8*)d_ws;                               // 32 MiB: M*K i8 (natural)
  u8* wq = xq + (size_t)M_DIM * K_DIM;              // 16 MiB: N*K i8 (perm-scattered)
  float* sx = (float*)(wq + (size_t)N_DIM * K_DIM); // 32 KiB
  float* sw = sx + M_DIM;                           // 16 KiB

  hipLaunchKernelGGL(prep_all, dim3(N_DIM + M_DIM / 4), dim3(256), 0, stream,
                     x, cs, qw, perm, scales, zeros, xq, wq, sx, sw);
  hipLaunchKernelGGL(gemm_i8, dim3((M_DIM / BM) * (N_DIM / BN)), dim3(256), 0,
                     stream, xq, wq, sx, sw, bias, out);
}